// Round 17
// baseline (230.723 us; speedup 1.0000x reference)
//
#include <hip/hip_runtime.h>
#include <hip/hip_bf16.h>

#define NSESS 2048
#define NI 64      // I
#define LL 63      // L = I-1
#define EE 256
#define HH 128
#define GG 384     // 3H

typedef __attribute__((ext_vector_type(8))) short short8;
typedef __attribute__((ext_vector_type(4))) float f32x4;

static __device__ __forceinline__ unsigned short f2b(float f) {
  union { float f; unsigned u; } v; v.f = f;
  unsigned r = (v.u + 0x7FFFu + ((v.u >> 16) & 1u)) >> 16;
  return (unsigned short)r;
}
static __device__ __forceinline__ float b2f(unsigned short s) {
  union { unsigned u; float f; } v; v.u = ((unsigned)s) << 16;
  return v.f;
}
static __device__ __forceinline__ float sigmoidf_(float x) {
  return 1.f / (1.f + __expf(-x));
}
static __device__ __forceinline__ float tanh2_(float y) {
  float e = __expf(2.f * y);            // inf-safe
  return 1.f - 2.f / (1.f + e);
}
// LDS-only barrier: waits ds ops, does NOT drain vmcnt.
static __device__ __forceinline__ void barrier_lds_only() {
  asm volatile("s_waitcnt lgkmcnt(0)" ::: "memory");
  __builtin_amdgcn_sched_barrier(0);
  __builtin_amdgcn_s_barrier();
  __builtin_amdgcn_sched_barrier(0);
}
// async global->LDS, 16B only (HW-verified width)
static __device__ __forceinline__ void gload_lds16(const void* g, void* l) {
  __builtin_amdgcn_global_load_lds(
      (const __attribute__((address_space(1))) unsigned int*)g,
      (__attribute__((address_space(3))) unsigned int*)l, 16, 0, 0);
}

// ---------------- K1: per-session prep ----------------
__global__ __launch_bounds__(64) void prep_kernel(const int* __restrict__ item_id,
                                                  const int* __restrict__ eval_from,
                                                  const int* __restrict__ u_type,
                                                  int* __restrict__ len_in,
                                                  int* __restrict__ inp,
                                                  float* __restrict__ out) {
  int n = blockIdx.x;          // session
  int lane = threadIdx.x;      // 0..63
  int b = n >> 5, s = n & 31;
  int allow = (s >= eval_from[b]) ? 1 : 0;
  int id = item_id[n * NI + lane];
  if (id < 0) id = 0;
  id *= allow;
  unsigned long long m = __ballot(id != 0);
  int length = __popcll(m);
  int li = length - 1;
  int tv = __shfl(id, (length > 0) ? (length - 1) : 0, 64);
  int target = (length > 0) ? tv : 0;
  if (lane < LL) inp[n * LL + lane] = (lane < li) ? id : 0;
  if (lane == 0) {
    len_in[n] = li;
    out[NSESS * 256 + n] = (float)target;            // Output 1: target
    out[NSESS * 256 + NSESS + n] = (float)u_type[b]; // Output 2: u
  }
}

// ---------------- K2: weights -> bf16 ----------------
__global__ __launch_bounds__(256) void cvt_weights(const float* __restrict__ W_ih,
                                                   const float* __restrict__ W_hh,
                                                   const float* __restrict__ W_a1,
                                                   unsigned short* __restrict__ Wb,
                                                   unsigned short* __restrict__ Whs,
                                                   unsigned short* __restrict__ Wa1b) {
  int i = blockIdx.x * 256 + threadIdx.x;   // 98304 threads
  Wb[i] = f2b(W_ih[i]);
  if (i < GG * HH) Whs[i] = f2b(W_hh[i]);   // W_hh bf16 [384][128]
  if (i < HH * HH) Wa1b[i] = f2b(W_a1[i]);  // W_a1 bf16 [N][K]
}

// ---------------- K3: gi = emb[inp] @ W_ih^T + b_ih ----------------
// gi layout: [l][n][384] u16 (coalesced epilogue; sess-packed 8x-amplified writes).
__global__ __launch_bounds__(512, 2) void gemm_in(const float* __restrict__ emb,
                                                  const unsigned short* __restrict__ Wb,
                                                  const float* __restrict__ b_ih,
                                                  const int* __restrict__ inp,
                                                  unsigned short* __restrict__ gi) {
  constexpr int XP = 264;                      // padded row stride (u16)
  __shared__ unsigned short Ash[2][16 * XP];   // 16896 B

  const int t = threadIdx.x;
  const int lane = t & 63, w = t >> 6;
  const int ccol = lane & 15, kg = lane >> 4;
  const int g0 = w * 48;

  short8 bfr[3][8];
#pragma unroll
  for (int nt = 0; nt < 3; ++nt) {
    const unsigned short* wrow = Wb + (long)(g0 + nt * 16 + ccol) * EE + kg * 8;
#pragma unroll
    for (int c = 0; c < 8; ++c) bfr[nt][c] = *(const short8*)(wrow + c * 32);
  }
  float bias[3];
#pragma unroll
  for (int nt = 0; nt < 3; ++nt) bias[nt] = b_ih[g0 + nt * 16 + ccol];

  const int tile0 = blockIdx.x * 8;
  const int srow = t >> 5;            // 0..15 (staging row)
  const int scol = (t & 31) * 8;      // f32 elem offset within row

  {
    long rid = inp[tile0 * 16 + srow];
    const float* x = emb + rid * EE + scol;
    float4 a0 = *(const float4*)x, a1 = *(const float4*)(x + 4);
    short8 v;
    v[0]=(short)f2b(a0.x); v[1]=(short)f2b(a0.y); v[2]=(short)f2b(a0.z); v[3]=(short)f2b(a0.w);
    v[4]=(short)f2b(a1.x); v[5]=(short)f2b(a1.y); v[6]=(short)f2b(a1.z); v[7]=(short)f2b(a1.w);
    *(short8*)(&Ash[0][srow * XP + scol]) = v;
  }
  __syncthreads();

  for (int i = 0; i < 8; ++i) {
    const int cur = i & 1;
    const int m0 = (tile0 + i) * 16;

    float4 a0, a1;
    if (i + 1 < 8) {
      long rid = inp[(tile0 + i + 1) * 16 + srow];
      const float* x = emb + rid * EE + scol;
      a0 = *(const float4*)x; a1 = *(const float4*)(x + 4);
    }

    f32x4 acc[3];
#pragma unroll
    for (int nt = 0; nt < 3; ++nt)
      acc[nt] = (f32x4){bias[nt], bias[nt], bias[nt], bias[nt]};
#pragma unroll
    for (int c = 0; c < 8; ++c) {
      short8 af = *(const short8*)(&Ash[cur][ccol * XP + c * 32 + kg * 8]);
#pragma unroll
      for (int nt = 0; nt < 3; ++nt)
        acc[nt] = __builtin_amdgcn_mfma_f32_16x16x32_bf16(af, bfr[nt][c], acc[nt], 0, 0, 0);
    }

    // store: row m = m0+kg*4+j -> (n = m/63, l = m%63); gi[l][n][g]
    long base[4];
#pragma unroll
    for (int j = 0; j < 4; ++j) {
      int m = m0 + kg * 4 + j;
      int n = m / 63;
      int l = m - 63 * n;
      base[j] = ((long)l * NSESS + n) * GG;
    }
#pragma unroll
    for (int nt = 0; nt < 3; ++nt) {
      int g = g0 + nt * 16 + ccol;
#pragma unroll
      for (int j = 0; j < 4; ++j)
        gi[base[j] + g] = f2b(acc[nt][j]);
    }

    if (i + 1 < 8) {
      short8 v;
      v[0]=(short)f2b(a0.x); v[1]=(short)f2b(a0.y); v[2]=(short)f2b(a0.z); v[3]=(short)f2b(a0.w);
      v[4]=(short)f2b(a1.x); v[5]=(short)f2b(a1.y); v[6]=(short)f2b(a1.z); v[7]=(short)f2b(a1.w);
      *(short8*)(&Ash[cur ^ 1][srow * XP + scol]) = v;
    }
    barrier_lds_only();
  }
}

// ---------------- K4: GRU recurrence via MFMA, 4 sessions/WG, 512 WGs (2 WGs/CU) ----------------
// 8-step windows. Slab (8 x [4 sess][384] = 24576 B) double-buffered, staged 2
// windows ahead (3 x 16B/thread, uniform). h ring: 8 slots [4 sess][128] swz.
// 2 dumps/window (4 steps each, disjoint slot halves). LDS 53 KB -> 2 WGs/CU.
__global__ __launch_bounds__(512) void gru_mfma(const unsigned short* __restrict__ Whs,
                                                const float* __restrict__ b_hh,
                                                const unsigned short* __restrict__ gi,
                                                const int* __restrict__ len_in,
                                                unsigned short* __restrict__ outs,
                                                float* __restrict__ ht,
                                                float* __restrict__ out) {
  __shared__ unsigned short Gbuf[2 * 12288];  // 49152 B: [buf][8 steps][4 sess][384]
  __shared__ unsigned short ring[8 * 512];    // 8192 B: [slot][4 sess][128] swz

  const int t = threadIdx.x;
  const int w = t >> 6, lane = t & 63;
  const int ccol = lane & 15, kg = lane >> 4;
  const bool act = (kg == 0);
  const int n0 = blockIdx.x * 4;
  const int jh = w * 16 + ccol;
  const int rr = ccol & 3;

  short8 bfr[3][4];
#pragma unroll
  for (int cls = 0; cls < 3; ++cls) {
    const unsigned short* wrow = Whs + (long)(cls * HH + jh) * HH;
#pragma unroll
    for (int c = 0; c < 4; ++c)
      bfr[cls][c] = *(const short8*)(wrow + c * 32 + kg * 8);
  }
  float bh[3];
#pragma unroll
  for (int cls = 0; cls < 3; ++cls) bh[cls] = b_hh[cls * HH + jh];

  int li[4];
#pragma unroll
  for (int r = 0; r < 4; ++r) li[r] = act ? len_in[n0 + r] : 0;
  float hold[4] = {0.f, 0.f, 0.f, 0.f};

  for (int idx = t; idx < 8 * 512; idx += 512) ring[idx] = 0;

  // dump mapping: thread t -> (dl4 = t>>7, dsess = (t>>5)&3, dcol = (t&31)*4)
  const int dl4 = t >> 7, dsess = (t >> 5) & 3, dcol = (t & 31) * 4;
  const int dlen = len_in[n0 + dsess];

  auto do_stage = [&](int W2) {
    const int b = W2 & 1;
#pragma unroll
    for (int s = 0; s < 3; ++s) {
      int u = s * 512 + t;                 // 0..1535 (16B units)
      int ls = u / 192;                    // sub-step 0..7
      int off = (u - ls * 192) * 8;        // u16 offset within 1536-u16 slab
      int lg = 8 * W2 + ls; if (lg > 62) lg = 62;
      const unsigned short* src = gi + ((long)lg * NSESS + n0) * GG + off;
      gload_lds16(src, (char*)Gbuf + b * 24576 + u * 16);
    }
  };

  auto do_dump = [&](int W, int phase) {
    const int dl = 8 * W + phase * 4 + dl4;
    if (dl < LL) {
      const int slot = phase * 4 + dl4;
      uint2 hv = *(const uint2*)(ring + slot * 512 + dsess * HH + (dcol ^ (dsess << 3)));
      if (dl >= dlen) { hv.x = 0; hv.y = 0; }
      *(uint2*)(outs + ((long)(n0 + dsess) * LL + dl) * HH + dcol) = hv;
    }
  };

  do_stage(0);
  do_stage(1);
  asm volatile("s_waitcnt vmcnt(3)" ::: "memory");   // stage(0) landed
  __builtin_amdgcn_sched_barrier(0);
  barrier_lds_only();

  for (int W = 0; W < 8; ++W) {
    const unsigned short* gb_base = Gbuf + (W & 1) * 12288;
#pragma unroll
    for (int l2 = 0; l2 < 8; ++l2) {
      const int l = 8 * W + l2;
      if (l < LL) {
        // A frags: previous h from ring slot (l+7)&7; rows duplicated x4
        const unsigned short* rb = ring + ((l + 7) & 7) * 512 + rr * HH;
        short8 af[4];
#pragma unroll
        for (int c = 0; c < 4; ++c)
          af[c] = *(const short8*)(rb + ((c * 32 + kg * 8) ^ (rr << 3)));

        // gv: 12 scalar u16 reads (act lanes only)
        const unsigned short* gb = gb_base + l2 * 1536;
        float gvv[3][4];
        if (act) {
#pragma unroll
          for (int cls = 0; cls < 3; ++cls)
#pragma unroll
            for (int r = 0; r < 4; ++r)
              gvv[cls][r] = b2f(gb[r * GG + cls * HH + jh]);
        }

        f32x4 acc[3];
#pragma unroll
        for (int cls = 0; cls < 3; ++cls) {
          acc[cls] = (f32x4){bh[cls], bh[cls], bh[cls], bh[cls]};
#pragma unroll
          for (int c = 0; c < 4; ++c)
            acc[cls] = __builtin_amdgcn_mfma_f32_16x16x32_bf16(af[c], bfr[cls][c], acc[cls], 0, 0, 0);
        }

        if (act) {
          unsigned short* wrb = ring + (l & 7) * 512;
#pragma unroll
          for (int r = 0; r < 4; ++r) {
            float rg = sigmoidf_(gvv[0][r] + acc[0][r]);
            float zg = sigmoidf_(gvv[1][r] + acc[1][r]);
            float ng = tanh2_(gvv[2][r] + rg * acc[2][r]);
            float hnew = ng + zg * (hold[r] - ng);
            hold[r] = (l < li[r]) ? hnew : hold[r];
            wrb[r * HH + (jh ^ (r << 3))] = f2b(hold[r]);
          }
        }
        barrier_lds_only();
      }
      if (l2 == 3) do_dump(W, 0);   // slots 0-3 (steps 4-7 write slots 4-7: disjoint)
    }
    do_dump(W, 1);                   // slots 4-7 (next window writes 0-3: disjoint)
    if (W + 2 < 8) do_stage(W + 2);
    if (W < 6) {
      asm volatile("s_waitcnt vmcnt(5)" ::: "memory");  // drain stage(W+1)x3
      __builtin_amdgcn_sched_barrier(0);
      barrier_lds_only();
    } else if (W == 6) {
      asm volatile("s_waitcnt vmcnt(2)" ::: "memory");  // drain stage(7)x3
      __builtin_amdgcn_sched_barrier(0);
      barrier_lds_only();
    }
  }

  if (act) {
#pragma unroll
    for (int r = 0; r < 4; ++r) {
      int n = n0 + r;
      ht[(long)n * HH + jh] = hold[r];
      out[(long)n * 256 + HH + jh] = hold[r];
    }
  }
}

// ---------------- K5: attention via MFMA ----------------
__global__ __launch_bounds__(256) void attn(const unsigned short* __restrict__ outs,
                                            const float* __restrict__ ht,
                                            const unsigned short* __restrict__ Wa1b,
                                            const float* __restrict__ W_a2,
                                            const float* __restrict__ W_vt,
                                            const int* __restrict__ len_in,
                                            float* __restrict__ out) {
  constexpr int OP = HH + 8;               // padded row stride (u16)
  __shared__ unsigned short o_l[64 * OP];  // 17408 B
  __shared__ float q2s[HH];
  __shared__ float wvt[HH];
  __shared__ float hts[HH];
  __shared__ float aw[4][64];              // per-wave alpha partials
  __shared__ float alphas[64];

  const int n = blockIdx.x;
  const int t = threadIdx.x;
  const int lane = t & 63, wv = t >> 6;
  const int ccol = lane & 15, kg = lane >> 4;
  const int li = len_in[n];

  const unsigned* src = (const unsigned*)(outs + (long)n * LL * HH);
  for (int idx = t; idx < LL * 64; idx += 256) {
    int r = idx >> 6, c2 = idx & 63;
    ((unsigned*)(o_l + r * OP))[c2] = src[r * 64 + c2];
  }
  if (t < 64) ((unsigned*)(o_l + 63 * OP))[t] = 0;
  if (t < HH) { hts[t] = ht[(long)n * HH + t]; wvt[t] = W_vt[t]; }

  short8 bfr[2][4];
#pragma unroll
  for (int nt = 0; nt < 2; ++nt) {
    int G = wv * 32 + nt * 16 + ccol;
#pragma unroll
    for (int c = 0; c < 4; ++c)
      bfr[nt][c] = *(const short8*)(Wa1b + (long)G * HH + c * 32 + kg * 8);
  }
  __syncthreads();

  if (t < HH) {
    float a = 0.f;
    const float* w2 = W_a2 + t * HH;
    for (int k = 0; k < HH; ++k) a += hts[k] * w2[k];
    q2s[t] = a;
  }
  __syncthreads();

  f32x4 acc[4][2];
#pragma unroll
  for (int mt = 0; mt < 4; ++mt)
#pragma unroll
    for (int nt = 0; nt < 2; ++nt) acc[mt][nt] = (f32x4){0.f, 0.f, 0.f, 0.f};
#pragma unroll
  for (int mt = 0; mt < 4; ++mt) {
#pragma unroll
    for (int c = 0; c < 4; ++c) {
      short8 af = *(const short8*)(o_l + (mt * 16 + ccol) * OP + c * 32 + kg * 8);
#pragma unroll
      for (int nt = 0; nt < 2; ++nt)
        acc[mt][nt] = __builtin_amdgcn_mfma_f32_16x16x32_bf16(af, bfr[nt][c], acc[mt][nt], 0, 0, 0);
    }
  }

  float q2v[2], wvv[2];
#pragma unroll
  for (int nt = 0; nt < 2; ++nt) {
    int cg = wv * 32 + nt * 16 + ccol;
    q2v[nt] = q2s[cg]; wvv[nt] = wvt[cg];
  }
#pragma unroll
  for (int mt = 0; mt < 4; ++mt) {
    float part[4] = {0.f, 0.f, 0.f, 0.f};
#pragma unroll
    for (int nt = 0; nt < 2; ++nt)
#pragma unroll
      for (int j = 0; j < 4; ++j)
        part[j] += sigmoidf_(acc[mt][nt][j] + q2v[nt]) * wvv[nt];
#pragma unroll
    for (int j = 0; j < 4; ++j) {
#pragma unroll
      for (int off = 1; off < 16; off <<= 1)
        part[j] += __shfl_xor(part[j], off, 64);
    }
    if (ccol == 0) {
#pragma unroll
      for (int j = 0; j < 4; ++j) aw[wv][mt * 16 + kg * 4 + j] = part[j];
    }
  }
  __syncthreads();

  if (t < 64) {
    float s = aw[0][t] + aw[1][t] + aw[2][t] + aw[3][t];
    alphas[t] = (t < li) ? s : 0.f;
  }
  __syncthreads();

  if (t < HH) {
    float c = 0.f;
    for (int l = 0; l < LL; ++l) c = fmaf(alphas[l], b2f(o_l[l * OP + t]), c);
    out[(long)n * 256 + t] = c;
  }
}

extern "C" void kernel_launch(void* const* d_in, const int* in_sizes, int n_in,
                              void* d_out, int out_size, void* d_ws, size_t ws_size,
                              hipStream_t stream) {
  (void)in_sizes; (void)n_in; (void)out_size; (void)ws_size;
  const int* item_id   = (const int*)d_in[0];
  const int* eval_from = (const int*)d_in[1];
  const int* u_type    = (const int*)d_in[2];
  const float* emb     = (const float*)d_in[3];
  const float* W_ih    = (const float*)d_in[4];
  const float* W_hh    = (const float*)d_in[5];
  const float* b_ih    = (const float*)d_in[6];
  const float* b_hh    = (const float*)d_in[7];
  const float* W_a1    = (const float*)d_in[8];
  const float* W_a2    = (const float*)d_in[9];
  const float* W_vt    = (const float*)d_in[10];

  float* out = (float*)d_out;   // f32: reps[2048*256] | target[2048] | u[2048]
  char* ws = (char*)d_ws;
  int* len_in           = (int*)(ws + 0);                      //      8192 B
  int* inp              = (int*)(ws + 8192);                   //    516096 B
  unsigned short* Wb    = (unsigned short*)(ws + 524288);      //    196608 B
  unsigned short* Whs   = (unsigned short*)(ws + 720896);      //     98304 B
  float* ht             = (float*)(ws + 819200);               //   1048576 B
  unsigned short* gi    = (unsigned short*)(ws + 1867776);     //  99090432 B  [l][n][384]
  unsigned short* outs  = (unsigned short*)(ws + 100958208);   //  33030144 B -> ends 133988352
  unsigned short* Wa1b  = (unsigned short*)(ws + 133988352);   //     32768 B -> ends 134021120

  prep_kernel<<<NSESS, 64, 0, stream>>>(item_id, eval_from, u_type, len_in, inp, out);
  cvt_weights<<<384, 256, 0, stream>>>(W_ih, W_hh, W_a1, Wb, Whs, Wa1b);
  gemm_in<<<1008, 512, 0, stream>>>(emb, Wb, b_ih, inp, gi);
  gru_mfma<<<NSESS / 4, 512, 0, stream>>>(Whs, b_hh, gi, len_in, outs, ht, out);
  attn<<<NSESS, 512, 0, stream>>>(outs, ht, Wa1b, W_a2, W_vt, len_in, out);
}

// Round 18
// 163.000 us; speedup vs baseline: 1.4155x; 1.4155x over previous
//
#include <hip/hip_runtime.h>
#include <hip/hip_bf16.h>

#define NSESS 2048
#define NI 64      // I
#define LL 63      // L = I-1
#define EE 256
#define HH 128
#define GG 384     // 3H

typedef __attribute__((ext_vector_type(8))) short short8;
typedef __attribute__((ext_vector_type(4))) float f32x4;

static __device__ __forceinline__ unsigned short f2b(float f) {
  union { float f; unsigned u; } v; v.f = f;
  unsigned r = (v.u + 0x7FFFu + ((v.u >> 16) & 1u)) >> 16;
  return (unsigned short)r;
}
static __device__ __forceinline__ float b2f(unsigned short s) {
  union { unsigned u; float f; } v; v.u = ((unsigned)s) << 16;
  return v.f;
}
static __device__ __forceinline__ float sigmoidf_(float x) {
  return 1.f / (1.f + __expf(-x));
}
static __device__ __forceinline__ float tanh2_(float y) {
  float e = __expf(2.f * y);            // inf-safe
  return 1.f - 2.f / (1.f + e);
}
// LDS-only barrier: waits ds ops, does NOT drain vmcnt.
static __device__ __forceinline__ void barrier_lds_only() {
  asm volatile("s_waitcnt lgkmcnt(0)" ::: "memory");
  __builtin_amdgcn_sched_barrier(0);
  __builtin_amdgcn_s_barrier();
  __builtin_amdgcn_sched_barrier(0);
}

// ---------------- K1: per-session prep ----------------
__global__ __launch_bounds__(64) void prep_kernel(const int* __restrict__ item_id,
                                                  const int* __restrict__ eval_from,
                                                  const int* __restrict__ u_type,
                                                  int* __restrict__ len_in,
                                                  int* __restrict__ inp,
                                                  float* __restrict__ out) {
  int n = blockIdx.x;          // session
  int lane = threadIdx.x;      // 0..63
  int b = n >> 5, s = n & 31;
  int allow = (s >= eval_from[b]) ? 1 : 0;
  int id = item_id[n * NI + lane];
  if (id < 0) id = 0;
  id *= allow;
  unsigned long long m = __ballot(id != 0);
  int length = __popcll(m);
  int li = length - 1;
  int tv = __shfl(id, (length > 0) ? (length - 1) : 0, 64);
  int target = (length > 0) ? tv : 0;
  if (lane < LL) inp[n * LL + lane] = (lane < li) ? id : 0;
  if (lane == 0) {
    len_in[n] = li;
    out[NSESS * 256 + n] = (float)target;            // Output 1: target
    out[NSESS * 256 + NSESS + n] = (float)u_type[b]; // Output 2: u
  }
}

// ---------------- K2: weights -> bf16 ----------------
__global__ __launch_bounds__(256) void cvt_weights(const float* __restrict__ W_ih,
                                                   const float* __restrict__ W_hh,
                                                   const float* __restrict__ W_a1,
                                                   unsigned short* __restrict__ Wb,
                                                   unsigned short* __restrict__ Whs,
                                                   unsigned short* __restrict__ Wa1b) {
  int i = blockIdx.x * 256 + threadIdx.x;   // 98304 threads
  Wb[i] = f2b(W_ih[i]);
  if (i < GG * HH) Whs[i] = f2b(W_hh[i]);   // W_hh bf16 [384][128]
  if (i < HH * HH) Wa1b[i] = f2b(W_a1[i]);  // W_a1 bf16 [N][K]
}

// ---------------- K3: gi = emb[inp] @ W_ih^T + b_ih ----------------
// gi layout: [l][n][384] u16
__global__ __launch_bounds__(512, 2) void gemm_in(const float* __restrict__ emb,
                                                  const unsigned short* __restrict__ Wb,
                                                  const float* __restrict__ b_ih,
                                                  const int* __restrict__ inp,
                                                  unsigned short* __restrict__ gi) {
  constexpr int XP = 264;                      // padded row stride (u16)
  __shared__ unsigned short Ash[2][16 * XP];   // 16896 B

  const int t = threadIdx.x;
  const int lane = t & 63, w = t >> 6;
  const int ccol = lane & 15, kg = lane >> 4;
  const int g0 = w * 48;

  short8 bfr[3][8];
#pragma unroll
  for (int nt = 0; nt < 3; ++nt) {
    const unsigned short* wrow = Wb + (long)(g0 + nt * 16 + ccol) * EE + kg * 8;
#pragma unroll
    for (int c = 0; c < 8; ++c) bfr[nt][c] = *(const short8*)(wrow + c * 32);
  }
  float bias[3];
#pragma unroll
  for (int nt = 0; nt < 3; ++nt) bias[nt] = b_ih[g0 + nt * 16 + ccol];

  const int tile0 = blockIdx.x * 8;
  const int srow = t >> 5;            // 0..15 (staging row)
  const int scol = (t & 31) * 8;      // f32 elem offset within row

  {
    long rid = inp[tile0 * 16 + srow];
    const float* x = emb + rid * EE + scol;
    float4 a0 = *(const float4*)x, a1 = *(const float4*)(x + 4);
    short8 v;
    v[0]=(short)f2b(a0.x); v[1]=(short)f2b(a0.y); v[2]=(short)f2b(a0.z); v[3]=(short)f2b(a0.w);
    v[4]=(short)f2b(a1.x); v[5]=(short)f2b(a1.y); v[6]=(short)f2b(a1.z); v[7]=(short)f2b(a1.w);
    *(short8*)(&Ash[0][srow * XP + scol]) = v;
  }
  __syncthreads();

  for (int i = 0; i < 8; ++i) {
    const int cur = i & 1;
    const int m0 = (tile0 + i) * 16;

    float4 a0, a1;
    if (i + 1 < 8) {
      long rid = inp[(tile0 + i + 1) * 16 + srow];
      const float* x = emb + rid * EE + scol;
      a0 = *(const float4*)x; a1 = *(const float4*)(x + 4);
    }

    f32x4 acc[3];
#pragma unroll
    for (int nt = 0; nt < 3; ++nt)
      acc[nt] = (f32x4){bias[nt], bias[nt], bias[nt], bias[nt]};
#pragma unroll
    for (int c = 0; c < 8; ++c) {
      short8 af = *(const short8*)(&Ash[cur][ccol * XP + c * 32 + kg * 8]);
#pragma unroll
      for (int nt = 0; nt < 3; ++nt)
        acc[nt] = __builtin_amdgcn_mfma_f32_16x16x32_bf16(af, bfr[nt][c], acc[nt], 0, 0, 0);
    }

    long base[4];
#pragma unroll
    for (int j = 0; j < 4; ++j) {
      int m = m0 + kg * 4 + j;
      int n = m / 63;
      int l = m - 63 * n;
      base[j] = ((long)l * NSESS + n) * GG;
    }
#pragma unroll
    for (int nt = 0; nt < 3; ++nt) {
      int g = g0 + nt * 16 + ccol;
#pragma unroll
      for (int j = 0; j < 4; ++j)
        gi[base[j] + g] = f2b(acc[nt][j]);
    }

    if (i + 1 < 8) {
      short8 v;
      v[0]=(short)f2b(a0.x); v[1]=(short)f2b(a0.y); v[2]=(short)f2b(a0.z); v[3]=(short)f2b(a0.w);
      v[4]=(short)f2b(a1.x); v[5]=(short)f2b(a1.y); v[6]=(short)f2b(a1.z); v[7]=(short)f2b(a1.w);
      *(short8*)(&Ash[cur ^ 1][srow * XP + scol]) = v;
    }
    barrier_lds_only();
  }
}

// ---------------- K4: GRU via MFMA, 16 sess/WG, 128 WGs, minimal step loop ----------------
// Per step/wave: 4 ds_read_b128 (h) + 12 MFMA + all-lane gate math + 4 ds_write_b16.
// gi read DIRECTLY global->reg, prefetched 2 steps deep (no LDS staging, no vmcnt asm).
// h ring: 8 slots [16 sess][128] XOR-swizzled (32 KB). outs dumped every 4 steps.
__global__ __launch_bounds__(512) void gru_mfma(const unsigned short* __restrict__ Whs,
                                                const float* __restrict__ b_hh,
                                                const unsigned short* __restrict__ gi,
                                                const int* __restrict__ len_in,
                                                unsigned short* __restrict__ outs,
                                                float* __restrict__ ht,
                                                float* __restrict__ out) {
  __shared__ unsigned short ring[8 * 2048];   // 32768 B: [slot][16 sess][128] swz
  __shared__ int lens_s[16];

  const int t = threadIdx.x;
  const int w = t >> 6, lane = t & 63;
  const int ccol = lane & 15, kg = lane >> 4;
  const int sbase = kg * 4;
  const int n0 = blockIdx.x * 16;
  const int jh = w * 16 + ccol;

  short8 bfr[3][4];
#pragma unroll
  for (int cls = 0; cls < 3; ++cls) {
    const unsigned short* wrow = Whs + (long)(cls * HH + jh) * HH;
#pragma unroll
    for (int c = 0; c < 4; ++c)
      bfr[cls][c] = *(const short8*)(wrow + c * 32 + kg * 8);
  }
  float bh[3];
#pragma unroll
  for (int cls = 0; cls < 3; ++cls) bh[cls] = b_hh[cls * HH + jh];

  int li[4];
#pragma unroll
  for (int r = 0; r < 4; ++r) li[r] = len_in[n0 + sbase + r];
  float hold[4] = {0.f, 0.f, 0.f, 0.f};

  for (int idx = t; idx < 8 * 2048; idx += 512) ring[idx] = 0;
  if (t < 16) lens_s[t] = len_in[n0 + t];

  // per-lane gi base (step stride = NSESS*GG elements)
  const unsigned short* gbase = gi + (long)(n0 + sbase) * GG + jh;
  const long lstride = (long)NSESS * GG;
  // 12 values per step: k = cls*4 + r -> offset r*GG + cls*HH
#define GADDR(l, cls, r) (gbase + (long)(l) * lstride + (r) * GG + (cls) * HH)

  unsigned short gA[12], gB[12];   // even-step / odd-step prefetch buffers
#pragma unroll
  for (int k = 0; k < 12; ++k) gA[k] = *GADDR(0, k >> 2, k & 3);
#pragma unroll
  for (int k = 0; k < 12; ++k) gB[k] = *GADDR(1, k >> 2, k & 3);

  barrier_lds_only();

  for (int W = 0; W < 16; ++W) {
#pragma unroll
    for (int l2 = 0; l2 < 4; ++l2) {
      const int l = 4 * W + l2;
      if (l < LL) {
        // unpack this step's gi from the static buffer (l&1 == l2&1)
        float gvv[12];
        if ((l2 & 1) == 0) {
#pragma unroll
          for (int k = 0; k < 12; ++k) gvv[k] = b2f(gA[k]);
        } else {
#pragma unroll
          for (int k = 0; k < 12; ++k) gvv[k] = b2f(gB[k]);
        }
        // prefetch step l+2 into the buffer just consumed
        if (l + 2 < LL) {
          if ((l2 & 1) == 0) {
#pragma unroll
            for (int k = 0; k < 12; ++k) gA[k] = *GADDR(l + 2, k >> 2, k & 3);
          } else {
#pragma unroll
            for (int k = 0; k < 12; ++k) gB[k] = *GADDR(l + 2, k >> 2, k & 3);
          }
        }

        // A frags: previous h from ring slot (l+7)&7; session = ccol
        const unsigned short* rb = ring + ((l + 7) & 7) * 2048 + ccol * HH;
        short8 af[4];
#pragma unroll
        for (int c = 0; c < 4; ++c)
          af[c] = *(const short8*)(rb + ((c * 32 + kg * 8) ^ ((ccol & 7) << 3)));

        f32x4 acc[3];
#pragma unroll
        for (int cls = 0; cls < 3; ++cls) {
          acc[cls] = (f32x4){bh[cls], bh[cls], bh[cls], bh[cls]};
#pragma unroll
          for (int c = 0; c < 4; ++c)
            acc[cls] = __builtin_amdgcn_mfma_f32_16x16x32_bf16(af[c], bfr[cls][c], acc[cls], 0, 0, 0);
        }

        // gate math: ALL 64 lanes useful (16 sessions); session = sbase + r
        unsigned short* wrb = ring + (l & 7) * 2048;
#pragma unroll
        for (int r = 0; r < 4; ++r) {
          float rg = sigmoidf_(gvv[0 * 4 + r] + acc[0][r]);
          float zg = sigmoidf_(gvv[1 * 4 + r] + acc[1][r]);
          float ng = tanh2_(gvv[2 * 4 + r] + rg * acc[2][r]);
          float hnew = ng + zg * (hold[r] - ng);
          hold[r] = (l < li[r]) ? hnew : hold[r];
          int sess = sbase + r;
          wrb[sess * HH + (jh ^ ((sess & 7) << 3))] = f2b(hold[r]);
        }
        barrier_lds_only();
      }
    }

    // dump window W (4 steps x 16 sess x 128 = 1024 short8 units), 2 per thread
#pragma unroll
    for (int half = 0; half < 2; ++half) {
      int idx = half * 512 + t;
      int dl2 = idx >> 8, sess = (idx >> 4) & 15, col8 = (idx & 15) * 8;
      int dl = 4 * W + dl2;
      if (dl < LL) {
        int slot = (W & 1) * 4 + dl2;
        short8 hv = *(const short8*)(ring + slot * 2048 + sess * HH +
                                     (col8 ^ ((sess & 7) << 3)));
        if (dl >= lens_s[sess]) hv = (short8){0, 0, 0, 0, 0, 0, 0, 0};
        *(short8*)(outs + ((long)(n0 + sess) * LL + dl) * HH + col8) = hv;
      }
    }
  }
#undef GADDR

#pragma unroll
  for (int r = 0; r < 4; ++r) {
    int n = n0 + sbase + r;
    ht[(long)n * HH + jh] = hold[r];
    out[(long)n * 256 + HH + jh] = hold[r];
  }
}

// ---------------- K5: attention via MFMA ----------------
__global__ __launch_bounds__(256) void attn(const unsigned short* __restrict__ outs,
                                            const float* __restrict__ ht,
                                            const unsigned short* __restrict__ Wa1b,
                                            const float* __restrict__ W_a2,
                                            const float* __restrict__ W_vt,
                                            const int* __restrict__ len_in,
                                            float* __restrict__ out) {
  constexpr int OP = HH + 8;               // padded row stride (u16)
  __shared__ unsigned short o_l[64 * OP];  // 17408 B
  __shared__ float q2s[HH];
  __shared__ float wvt[HH];
  __shared__ float hts[HH];
  __shared__ float aw[4][64];              // per-wave alpha partials
  __shared__ float alphas[64];

  const int n = blockIdx.x;
  const int t = threadIdx.x;
  const int lane = t & 63, wv = t >> 6;
  const int ccol = lane & 15, kg = lane >> 4;
  const int li = len_in[n];

  const unsigned* src = (const unsigned*)(outs + (long)n * LL * HH);
  for (int idx = t; idx < LL * 64; idx += 256) {
    int r = idx >> 6, c2 = idx & 63;
    ((unsigned*)(o_l + r * OP))[c2] = src[r * 64 + c2];
  }
  if (t < 64) ((unsigned*)(o_l + 63 * OP))[t] = 0;
  if (t < HH) { hts[t] = ht[(long)n * HH + t]; wvt[t] = W_vt[t]; }

  short8 bfr[2][4];
#pragma unroll
  for (int nt = 0; nt < 2; ++nt) {
    int G = wv * 32 + nt * 16 + ccol;
#pragma unroll
    for (int c = 0; c < 4; ++c)
      bfr[nt][c] = *(const short8*)(Wa1b + (long)G * HH + c * 32 + kg * 8);
  }
  __syncthreads();

  if (t < HH) {
    float a = 0.f;
    const float* w2 = W_a2 + t * HH;
    for (int k = 0; k < HH; ++k) a += hts[k] * w2[k];
    q2s[t] = a;
  }
  __syncthreads();

  f32x4 acc[4][2];
#pragma unroll
  for (int mt = 0; mt < 4; ++mt)
#pragma unroll
    for (int nt = 0; nt < 2; ++nt) acc[mt][nt] = (f32x4){0.f, 0.f, 0.f, 0.f};
#pragma unroll
  for (int mt = 0; mt < 4; ++mt) {
#pragma unroll
    for (int c = 0; c < 4; ++c) {
      short8 af = *(const short8*)(o_l + (mt * 16 + ccol) * OP + c * 32 + kg * 8);
#pragma unroll
      for (int nt = 0; nt < 2; ++nt)
        acc[mt][nt] = __builtin_amdgcn_mfma_f32_16x16x32_bf16(af, bfr[nt][c], acc[mt][nt], 0, 0, 0);
    }
  }

  float q2v[2], wvv[2];
#pragma unroll
  for (int nt = 0; nt < 2; ++nt) {
    int cg = wv * 32 + nt * 16 + ccol;
    q2v[nt] = q2s[cg]; wvv[nt] = wvt[cg];
  }
#pragma unroll
  for (int mt = 0; mt < 4; ++mt) {
    float part[4] = {0.f, 0.f, 0.f, 0.f};
#pragma unroll
    for (int nt = 0; nt < 2; ++nt)
#pragma unroll
      for (int j = 0; j < 4; ++j)
        part[j] += sigmoidf_(acc[mt][nt][j] + q2v[nt]) * wvv[nt];
#pragma unroll
    for (int j = 0; j < 4; ++j) {
#pragma unroll
      for (int off = 1; off < 16; off <<= 1)
        part[j] += __shfl_xor(part[j], off, 64);
    }
    if (ccol == 0) {
#pragma unroll
      for (int j = 0; j < 4; ++j) aw[wv][mt * 16 + kg * 4 + j] = part[j];
    }
  }
  __syncthreads();

  if (t < 64) {
    float s = aw[0][t] + aw[1][t] + aw[2][t] + aw[3][t];
    alphas[t] = (t < li) ? s : 0.f;
  }
  __syncthreads();

  if (t < HH) {
    float c = 0.f;
    for (int l = 0; l < LL; ++l) c = fmaf(alphas[l], b2f(o_l[l * OP + t]), c);
    out[(long)n * 256 + t] = c;
  }
}

extern "C" void kernel_launch(void* const* d_in, const int* in_sizes, int n_in,
                              void* d_out, int out_size, void* d_ws, size_t ws_size,
                              hipStream_t stream) {
  (void)in_sizes; (void)n_in; (void)out_size; (void)ws_size;
  const int* item_id   = (const int*)d_in[0];
  const int* eval_from = (const int*)d_in[1];
  const int* u_type    = (const int*)d_in[2];
  const float* emb     = (const float*)d_in[3];
  const float* W_ih    = (const float*)d_in[4];
  const float* W_hh    = (const float*)d_in[5];
  const float* b_ih    = (const float*)d_in[6];
  const float* b_hh    = (const float*)d_in[7];
  const float* W_a1    = (const float*)d_in[8];
  const float* W_a2    = (const float*)d_in[9];
  const float* W_vt    = (const float*)d_in[10];

  float* out = (float*)d_out;   // f32: reps[2048*256] | target[2048] | u[2048]
  char* ws = (char*)d_ws;
  int* len_in           = (int*)(ws + 0);                      //      8192 B
  int* inp              = (int*)(ws + 8192);                   //    516096 B
  unsigned short* Wb    = (unsigned short*)(ws + 524288);      //    196608 B
  unsigned short* Whs   = (unsigned short*)(ws + 720896);      //     98304 B
  float* ht             = (float*)(ws + 819200);               //   1048576 B
  unsigned short* gi    = (unsigned short*)(ws + 1867776);     //  99090432 B  [l][n][384]
  unsigned short* outs  = (unsigned short*)(ws + 100958208);   //  33030144 B -> ends 133988352
  unsigned short* Wa1b  = (unsigned short*)(ws + 133988352);   //     32768 B -> ends 134021120

  prep_kernel<<<NSESS, 64, 0, stream>>>(item_id, eval_from, u_type, len_in, inp, out);
  cvt_weights<<<384, 256, 0, stream>>>(W_ih, W_hh, W_a1, Wb, Whs, Wa1b);
  gemm_in<<<1008, 512, 0, stream>>>(emb, Wb, b_ih, inp, gi);
  gru_mfma<<<NSESS / 16, 512, 0, stream>>>(Whs, b_hh, gi, len_in, outs, ht, out);
  attn<<<NSESS, 512, 0, stream>>>(outs, ht, Wa1b, W_a2, W_vt, len_in, out);
}

// Round 19
// 139.808 us; speedup vs baseline: 1.6503x; 1.1659x over previous
//
#include <hip/hip_runtime.h>
#include <hip/hip_bf16.h>

#define NSESS 2048
#define NI 64      // I
#define LL 63      // L = I-1
#define EE 256
#define HH 128
#define GG 384     // 3H

typedef __attribute__((ext_vector_type(8))) short short8;
typedef __attribute__((ext_vector_type(4))) float f32x4;

static __device__ __forceinline__ unsigned short f2b(float f) {
  union { float f; unsigned u; } v; v.f = f;
  unsigned r = (v.u + 0x7FFFu + ((v.u >> 16) & 1u)) >> 16;
  return (unsigned short)r;
}
static __device__ __forceinline__ float b2f(unsigned short s) {
  union { unsigned u; float f; } v; v.u = ((unsigned)s) << 16;
  return v.f;
}
static __device__ __forceinline__ float lo16(unsigned u) {
  union { unsigned v; float f; } x; x.v = u << 16; return x.f;
}
static __device__ __forceinline__ float hi16(unsigned u) {
  union { unsigned v; float f; } x; x.v = u & 0xFFFF0000u; return x.f;
}
static __device__ __forceinline__ float sigmoidf_(float x) {
  return 1.f / (1.f + __expf(-x));
}
static __device__ __forceinline__ float tanh2_(float y) {
  float e = __expf(2.f * y);            // inf-safe
  return 1.f - 2.f / (1.f + e);
}
// LDS-only barrier: waits ds ops, does NOT drain vmcnt.
static __device__ __forceinline__ void barrier_lds_only() {
  asm volatile("s_waitcnt lgkmcnt(0)" ::: "memory");
  __builtin_amdgcn_sched_barrier(0);
  __builtin_amdgcn_s_barrier();
  __builtin_amdgcn_sched_barrier(0);
}

// ---------------- K1: per-session prep ----------------
__global__ __launch_bounds__(64) void prep_kernel(const int* __restrict__ item_id,
                                                  const int* __restrict__ eval_from,
                                                  const int* __restrict__ u_type,
                                                  int* __restrict__ len_in,
                                                  int* __restrict__ inp,
                                                  float* __restrict__ out) {
  int n = blockIdx.x;          // session
  int lane = threadIdx.x;      // 0..63
  int b = n >> 5, s = n & 31;
  int allow = (s >= eval_from[b]) ? 1 : 0;
  int id = item_id[n * NI + lane];
  if (id < 0) id = 0;
  id *= allow;
  unsigned long long m = __ballot(id != 0);
  int length = __popcll(m);
  int li = length - 1;
  int tv = __shfl(id, (length > 0) ? (length - 1) : 0, 64);
  int target = (length > 0) ? tv : 0;
  if (lane < LL) inp[n * LL + lane] = (lane < li) ? id : 0;
  if (lane == 0) {
    len_in[n] = li;
    out[NSESS * 256 + n] = (float)target;            // Output 1: target
    out[NSESS * 256 + NSESS + n] = (float)u_type[b]; // Output 2: u
  }
}

// ---------------- K2: weights -> bf16 ----------------
__global__ __launch_bounds__(256) void cvt_weights(const float* __restrict__ W_ih,
                                                   const float* __restrict__ W_hh,
                                                   const float* __restrict__ W_a1,
                                                   unsigned short* __restrict__ Wb,
                                                   unsigned short* __restrict__ Whs,
                                                   unsigned short* __restrict__ Wa1b) {
  int i = blockIdx.x * 256 + threadIdx.x;   // 98304 threads
  Wb[i] = f2b(W_ih[i]);
  if (i < GG * HH) Whs[i] = f2b(W_hh[i]);   // W_hh bf16 [384][128]
  if (i < HH * HH) Wa1b[i] = f2b(W_a1[i]);  // W_a1 bf16 [N][K]
}

// ---------------- K3: gi = emb[inp] @ W_ih^T + b_ih ----------------
// gi layout: [l][n][384] u16
__global__ __launch_bounds__(512, 2) void gemm_in(const float* __restrict__ emb,
                                                  const unsigned short* __restrict__ Wb,
                                                  const float* __restrict__ b_ih,
                                                  const int* __restrict__ inp,
                                                  unsigned short* __restrict__ gi) {
  constexpr int XP = 264;                      // padded row stride (u16)
  __shared__ unsigned short Ash[2][16 * XP];   // 16896 B

  const int t = threadIdx.x;
  const int lane = t & 63, w = t >> 6;
  const int ccol = lane & 15, kg = lane >> 4;
  const int g0 = w * 48;

  short8 bfr[3][8];
#pragma unroll
  for (int nt = 0; nt < 3; ++nt) {
    const unsigned short* wrow = Wb + (long)(g0 + nt * 16 + ccol) * EE + kg * 8;
#pragma unroll
    for (int c = 0; c < 8; ++c) bfr[nt][c] = *(const short8*)(wrow + c * 32);
  }
  float bias[3];
#pragma unroll
  for (int nt = 0; nt < 3; ++nt) bias[nt] = b_ih[g0 + nt * 16 + ccol];

  const int tile0 = blockIdx.x * 8;
  const int srow = t >> 5;            // 0..15 (staging row)
  const int scol = (t & 31) * 8;      // f32 elem offset within row

  {
    long rid = inp[tile0 * 16 + srow];
    const float* x = emb + rid * EE + scol;
    float4 a0 = *(const float4*)x, a1 = *(const float4*)(x + 4);
    short8 v;
    v[0]=(short)f2b(a0.x); v[1]=(short)f2b(a0.y); v[2]=(short)f2b(a0.z); v[3]=(short)f2b(a0.w);
    v[4]=(short)f2b(a1.x); v[5]=(short)f2b(a1.y); v[6]=(short)f2b(a1.z); v[7]=(short)f2b(a1.w);
    *(short8*)(&Ash[0][srow * XP + scol]) = v;
  }
  __syncthreads();

  for (int i = 0; i < 8; ++i) {
    const int cur = i & 1;
    const int m0 = (tile0 + i) * 16;

    float4 a0, a1;
    if (i + 1 < 8) {
      long rid = inp[(tile0 + i + 1) * 16 + srow];
      const float* x = emb + rid * EE + scol;
      a0 = *(const float4*)x; a1 = *(const float4*)(x + 4);
    }

    f32x4 acc[3];
#pragma unroll
    for (int nt = 0; nt < 3; ++nt)
      acc[nt] = (f32x4){bias[nt], bias[nt], bias[nt], bias[nt]};
#pragma unroll
    for (int c = 0; c < 8; ++c) {
      short8 af = *(const short8*)(&Ash[cur][ccol * XP + c * 32 + kg * 8]);
#pragma unroll
      for (int nt = 0; nt < 3; ++nt)
        acc[nt] = __builtin_amdgcn_mfma_f32_16x16x32_bf16(af, bfr[nt][c], acc[nt], 0, 0, 0);
    }

    long base[4];
#pragma unroll
    for (int j = 0; j < 4; ++j) {
      int m = m0 + kg * 4 + j;
      int n = m / 63;
      int l = m - 63 * n;
      base[j] = ((long)l * NSESS + n) * GG;
    }
#pragma unroll
    for (int nt = 0; nt < 3; ++nt) {
      int g = g0 + nt * 16 + ccol;
#pragma unroll
      for (int j = 0; j < 4; ++j)
        gi[base[j] + g] = f2b(acc[nt][j]);
    }

    if (i + 1 < 8) {
      short8 v;
      v[0]=(short)f2b(a0.x); v[1]=(short)f2b(a0.y); v[2]=(short)f2b(a0.z); v[3]=(short)f2b(a0.w);
      v[4]=(short)f2b(a1.x); v[5]=(short)f2b(a1.y); v[6]=(short)f2b(a1.z); v[7]=(short)f2b(a1.w);
      *(short8*)(&Ash[cur ^ 1][srow * XP + scol]) = v;
    }
    barrier_lds_only();
  }
}

// ---------------- K4: GRU via MFMA, SWAPPED operands: C[session][gate] ----------------
// 128 WGs x 512 thr, 16 sess/WG. mfma(A=W_hh, B=h): lane owns session=ccol,
// gate positions p0..p0+3 (p0 = w*16+kg*4). Per step/wave: 4 ds_read_b128 (h) +
// 3 global b64 gv (prefetched 2 deep) + 12 MFMA + gates + 1 ds_write_b64 +
// 1 global b64 outs store + 1 barrier. Ring: 2 slots [16][128] swz (8 KB).
__global__ __launch_bounds__(512) void gru_mfma(const unsigned short* __restrict__ Whs,
                                                const float* __restrict__ b_hh,
                                                const unsigned short* __restrict__ gi,
                                                const int* __restrict__ len_in,
                                                unsigned short* __restrict__ outs,
                                                float* __restrict__ ht,
                                                float* __restrict__ out) {
  __shared__ unsigned short ring[2 * 2048];   // 8192 B: [slot][16 sess][128] swz16B

  const int t = threadIdx.x;
  const int w = t >> 6, lane = t & 63;
  const int ccol = lane & 15, kg = lane >> 4;
  const int n0 = blockIdx.x * 16;
  const int jh = w * 16 + ccol;     // gate index within cls for the A-frag row
  const int p0 = w * 16 + kg * 4;   // this lane's 4 gate positions (C rows)
  const int swz = (ccol & 7) << 3;  // u16-unit XOR key (16B-granular in bytes)

  // A-frags: W_hh rows cls*128 + jh (same load pattern as before, now used as A)
  short8 bfr[3][4];
#pragma unroll
  for (int cls = 0; cls < 3; ++cls) {
    const unsigned short* wrow = Whs + (long)(cls * HH + jh) * HH;
#pragma unroll
    for (int c = 0; c < 4; ++c)
      bfr[cls][c] = *(const short8*)(wrow + c * 32 + kg * 8);
  }
  // bias: 4 consecutive positions per cls
  f32x4 bhv[3];
#pragma unroll
  for (int cls = 0; cls < 3; ++cls)
    bhv[cls] = *(const f32x4*)(b_hh + cls * HH + p0);

  const int li = len_in[n0 + ccol];
  float hold[4] = {0.f, 0.f, 0.f, 0.f};

  for (int idx = t; idx < 2 * 2048; idx += 512) ring[idx] = 0;

  // gv: 3 x uint2 per step at gi[(l*NSESS + n0+ccol)*GG + cls*128 + p0]
  const unsigned short* gbase = gi + (long)(n0 + ccol) * GG + p0;
  const long lstride = (long)NSESS * GG;
#define GA(l, cls) ((const uint2*)(gbase + (long)(l) * lstride + (cls) * HH))

  uint2 gA[3], gB[3];
#pragma unroll
  for (int cls = 0; cls < 3; ++cls) gA[cls] = *GA(0, cls);
#pragma unroll
  for (int cls = 0; cls < 3; ++cls) gB[cls] = *GA(1, cls);

  barrier_lds_only();

  auto step = [&](int l, uint2 (&gbuf)[3]) {
    // unpack gv
    float gvv[3][4];
#pragma unroll
    for (int cls = 0; cls < 3; ++cls) {
      gvv[cls][0] = lo16(gbuf[cls].x); gvv[cls][1] = hi16(gbuf[cls].x);
      gvv[cls][2] = lo16(gbuf[cls].y); gvv[cls][3] = hi16(gbuf[cls].y);
    }
    // prefetch l+2 into the buffer just consumed
    if (l + 2 < LL) {
#pragma unroll
      for (int cls = 0; cls < 3; ++cls) gbuf[cls] = *GA(l + 2, cls);
    }

    // B-frags: previous h from ring slot (l+1)&1, session = ccol
    const unsigned short* rb = ring + ((l + 1) & 1) * 2048 + ccol * HH;
    short8 hf[4];
#pragma unroll
    for (int c = 0; c < 4; ++c)
      hf[c] = *(const short8*)(rb + ((c * 32 + kg * 8) ^ swz));

    // gh[gate = cls*128 + p0 + j][session = ccol]
    f32x4 acc[3];
#pragma unroll
    for (int cls = 0; cls < 3; ++cls) {
      acc[cls] = bhv[cls];
#pragma unroll
      for (int c = 0; c < 4; ++c)
        acc[cls] = __builtin_amdgcn_mfma_f32_16x16x32_bf16(bfr[cls][c], hf[c], acc[cls], 0, 0, 0);
    }

    // gate math: 4 h-columns (p0..p0+3) of session ccol
    bool valid = (l < li);
#pragma unroll
    for (int j = 0; j < 4; ++j) {
      float rg = sigmoidf_(gvv[0][j] + acc[0][j]);
      float zg = sigmoidf_(gvv[1][j] + acc[1][j]);
      float ng = tanh2_(gvv[2][j] + rg * acc[2][j]);
      float hnew = ng + zg * (hold[j] - ng);
      hold[j] = valid ? hnew : hold[j];
    }
    // pack retained h; write ring (b64, swizzled) + outs (b64, masked)
    uint2 hp;
    hp.x = (unsigned)f2b(hold[0]) | ((unsigned)f2b(hold[1]) << 16);
    hp.y = (unsigned)f2b(hold[2]) | ((unsigned)f2b(hold[3]) << 16);
    *(uint2*)(ring + (l & 1) * 2048 + ccol * HH + (((w * 16 + kg * 4)) ^ swz)) = hp;
    uint2 ov = valid ? hp : (uint2){0u, 0u};
    *(uint2*)(outs + ((long)(n0 + ccol) * LL + l) * HH + p0) = ov;
    barrier_lds_only();
  };

  for (int b2 = 0; b2 < 31; ++b2) {
    step(2 * b2, gA);
    step(2 * b2 + 1, gB);
  }
  step(62, gA);
#undef GA

  // epilogue: ht + reps[:,128+p0..] for session ccol
  f32x4 hv = {hold[0], hold[1], hold[2], hold[3]};
  *(f32x4*)(ht + (long)(n0 + ccol) * HH + p0) = hv;
  *(f32x4*)(out + (long)(n0 + ccol) * 256 + HH + p0) = hv;
}

// ---------------- K5: attention via MFMA ----------------
__global__ __launch_bounds__(256) void attn(const unsigned short* __restrict__ outs,
                                            const float* __restrict__ ht,
                                            const unsigned short* __restrict__ Wa1b,
                                            const float* __restrict__ W_a2,
                                            const float* __restrict__ W_vt,
                                            const int* __restrict__ len_in,
                                            float* __restrict__ out) {
  constexpr int OP = HH + 8;               // padded row stride (u16)
  __shared__ unsigned short o_l[64 * OP];  // 17408 B
  __shared__ float q2s[HH];
  __shared__ float wvt[HH];
  __shared__ float hts[HH];
  __shared__ float aw[4][64];              // per-wave alpha partials
  __shared__ float alphas[64];

  const int n = blockIdx.x;
  const int t = threadIdx.x;
  const int lane = t & 63, wv = t >> 6;
  const int ccol = lane & 15, kg = lane >> 4;
  const int li = len_in[n];

  const unsigned* src = (const unsigned*)(outs + (long)n * LL * HH);
  for (int idx = t; idx < LL * 64; idx += 256) {
    int r = idx >> 6, c2 = idx & 63;
    ((unsigned*)(o_l + r * OP))[c2] = src[r * 64 + c2];
  }
  if (t < 64) ((unsigned*)(o_l + 63 * OP))[t] = 0;
  if (t < HH) { hts[t] = ht[(long)n * HH + t]; wvt[t] = W_vt[t]; }

  short8 bfr[2][4];
#pragma unroll
  for (int nt = 0; nt < 2; ++nt) {
    int G = wv * 32 + nt * 16 + ccol;
#pragma unroll
    for (int c = 0; c < 4; ++c)
      bfr[nt][c] = *(const short8*)(Wa1b + (long)G * HH + c * 32 + kg * 8);
  }
  __syncthreads();

  if (t < HH) {
    float a = 0.f;
    const float* w2 = W_a2 + t * HH;
    for (int k = 0; k < HH; ++k) a += hts[k] * w2[k];
    q2s[t] = a;
  }
  __syncthreads();

  f32x4 acc[4][2];
#pragma unroll
  for (int mt = 0; mt < 4; ++mt)
#pragma unroll
    for (int nt = 0; nt < 2; ++nt) acc[mt][nt] = (f32x4){0.f, 0.f, 0.f, 0.f};
#pragma unroll
  for (int mt = 0; mt < 4; ++mt) {
#pragma unroll
    for (int c = 0; c < 4; ++c) {
      short8 af = *(const short8*)(o_l + (mt * 16 + ccol) * OP + c * 32 + kg * 8);
#pragma unroll
      for (int nt = 0; nt < 2; ++nt)
        acc[mt][nt] = __builtin_amdgcn_mfma_f32_16x16x32_bf16(af, bfr[nt][c], acc[mt][nt], 0, 0, 0);
    }
  }

  float q2v[2], wvv[2];
#pragma unroll
  for (int nt = 0; nt < 2; ++nt) {
    int cg = wv * 32 + nt * 16 + ccol;
    q2v[nt] = q2s[cg]; wvv[nt] = wvt[cg];
  }
#pragma unroll
  for (int mt = 0; mt < 4; ++mt) {
    float part[4] = {0.f, 0.f, 0.f, 0.f};
#pragma unroll
    for (int nt = 0; nt < 2; ++nt)
#pragma unroll
      for (int j = 0; j < 4; ++j)
        part[j] += sigmoidf_(acc[mt][nt][j] + q2v[nt]) * wvv[nt];
#pragma unroll
    for (int j = 0; j < 4; ++j) {
#pragma unroll
      for (int off = 1; off < 16; off <<= 1)
        part[j] += __shfl_xor(part[j], off, 64);
    }
    if (ccol == 0) {
#pragma unroll
      for (int j = 0; j < 4; ++j) aw[wv][mt * 16 + kg * 4 + j] = part[j];
    }
  }
  __syncthreads();

  if (t < 64) {
    float s = aw[0][t] + aw[1][t] + aw[2][t] + aw[3][t];
    alphas[t] = (t < li) ? s : 0.f;
  }
  __syncthreads();

  if (t < HH) {
    float c = 0.f;
    for (int l = 0; l < LL; ++l) c = fmaf(alphas[l], b2f(o_l[l * OP + t]), c);
    out[(long)n * 256 + t] = c;
  }
}

extern "C" void kernel_launch(void* const* d_in, const int* in_sizes, int n_in,
                              void* d_out, int out_size, void* d_ws, size_t ws_size,
                              hipStream_t stream) {
  (void)in_sizes; (void)n_in; (void)out_size; (void)ws_size;
  const int* item_id   = (const int*)d_in[0];
  const int* eval_from = (const int*)d_in[1];
  const int* u_type    = (const int*)d_in[2];
  const float* emb     = (const float*)d_in[3];
  const float* W_ih    = (const float*)d_in[4];
  const float* W_hh    = (const float*)d_in[5];
  const float* b_ih    = (const float*)d_in[6];
  const float* b_hh    = (const float*)d_in[7];
  const float* W_a1    = (const float*)d_in[8];
  const float* W_a2    = (const float*)d_in[9];
  const float* W_vt    = (const float*)d_in[10];

  float* out = (float*)d_out;   // f32: reps[2048*256] | target[2048] | u[2048]
  char* ws = (char*)d_ws;
  int* len_in           = (int*)(ws + 0);                      //      8192 B
  int* inp              = (int*)(ws + 8192);                   //    516096 B
  unsigned short* Wb    = (unsigned short*)(ws + 524288);      //    196608 B
  unsigned short* Whs   = (unsigned short*)(ws + 720896);      //     98304 B
  float* ht             = (float*)(ws + 819200);               //   1048576 B
  unsigned short* gi    = (unsigned short*)(ws + 1867776);     //  99090432 B  [l][n][384]
  unsigned short* outs  = (unsigned short*)(ws + 100958208);   //  33030144 B -> ends 133988352
  unsigned short* Wa1b  = (unsigned short*)(ws + 133988352);   //     32768 B -> ends 134021120

  prep_kernel<<<NSESS, 64, 0, stream>>>(item_id, eval_from, u_type, len_in, inp, out);
  cvt_weights<<<384, 256, 0, stream>>>(W_ih, W_hh, W_a1, Wb, Whs, Wa1b);
  gemm_in<<<1008, 512, 0, stream>>>(emb, Wb, b_ih, inp, gi);
  gru_mfma<<<NSESS / 16, 512, 0, stream>>>(Whs, b_hh, gi, len_in, outs, ht, out);
  attn<<<NSESS, 512, 0, stream>>>(outs, ht, Wa1b, W_a2, W_vt, len_in, out);
}